// Round 1
// baseline (153.668 us; speedup 1.0000x reference)
//
#include <hip/hip_runtime.h>

#define NMODELS 128
#define SZ_IN 256
#define SZ_OUT 256
#define S_CHUNK 16

// Kernel 1: bucket samples by agent id.
// Single workgroup: LDS histogram -> serial prefix (128 entries) -> scatter.
// Writes off[0..NMODELS] and sorted[0..B) into workspace.
__global__ __launch_bounds__(256) void prep_kernel(const int* __restrict__ ids, int B,
                                                   int* __restrict__ off,
                                                   int* __restrict__ sorted) {
  __shared__ int cnt[NMODELS];
  __shared__ int pos[NMODELS];
  const int t = threadIdx.x;
  if (t < NMODELS) cnt[t] = 0;
  __syncthreads();
  for (int b = t; b < B; b += blockDim.x) atomicAdd(&cnt[ids[b]], 1);
  __syncthreads();
  if (t == 0) {
    int run = 0;
    for (int m = 0; m < NMODELS; ++m) {
      pos[m] = run;
      off[m] = run;
      run += cnt[m];
    }
    off[NMODELS] = run;
  }
  __syncthreads();
  for (int b = t; b < B; b += blockDim.x) {
    const int p = atomicAdd(&pos[ids[b]], 1);
    sorted[p] = b;
  }
}

// Kernel 2: grouped batched GEMV.
// blockIdx.y = model m; grid-stride over chunks of S_CHUNK samples of that model.
// thread t (0..255) owns output column o=t.
// Weight W[i][t] read once per chunk (coalesced), amortized over 16 samples.
// inp[s][i] is wave-uniform (sample idx readfirstlane'd) -> scalar loads + v_fmac sgpr operand.
__global__ __launch_bounds__(256) void linmulti_kernel(
    const float* __restrict__ inp, const float* __restrict__ wlut,
    const float* __restrict__ blut, const int* __restrict__ off,
    const int* __restrict__ sorted, float* __restrict__ out) {
  const int m = blockIdx.y;
  const int t = threadIdx.x;
  const int beg = off[m];
  const int end = off[m + 1];
  const int cnt = end - beg;
  if (cnt <= 0) return;

  const float* __restrict__ W = wlut + (size_t)m * (SZ_IN * SZ_OUT);
  const float bias_t = blut[m * SZ_OUT + t];

  const int nchunk = (cnt + S_CHUNK - 1) / S_CHUNK;
  for (int c = blockIdx.x; c < nchunk; c += gridDim.x) {
    const int start = beg + c * S_CHUNK;

    int idxs[S_CHUNK];
#pragma unroll
    for (int s = 0; s < S_CHUNK; ++s) {
      int p = start + s;
      if (p > end - 1) p = end - 1;  // clamp: padded slots recompute last sample, store is guarded
      idxs[s] = __builtin_amdgcn_readfirstlane(sorted[p]);
    }

    float acc[S_CHUNK];
#pragma unroll
    for (int s = 0; s < S_CHUNK; ++s) acc[s] = 0.0f;

#pragma unroll 1
    for (int i0 = 0; i0 < SZ_IN; i0 += 8) {
      float w[8];
#pragma unroll
      for (int j = 0; j < 8; ++j) w[j] = W[(i0 + j) * SZ_OUT + t];
#pragma unroll
      for (int s = 0; s < S_CHUNK; ++s) {
        const float* __restrict__ ir = inp + (size_t)idxs[s] * SZ_IN + i0;
#pragma unroll
        for (int j = 0; j < 8; ++j) acc[s] = fmaf(ir[j], w[j], acc[s]);
      }
    }

#pragma unroll
    for (int s = 0; s < S_CHUNK; ++s) {
      if (start + s < end) out[(size_t)idxs[s] * SZ_OUT + t] = acc[s] + bias_t;
    }
  }
}

extern "C" void kernel_launch(void* const* d_in, const int* in_sizes, int n_in,
                              void* d_out, int out_size, void* d_ws, size_t ws_size,
                              hipStream_t stream) {
  const float* inp = (const float*)d_in[0];
  const int* ids = (const int*)d_in[1];
  const float* wlut = (const float*)d_in[2];
  const float* blut = (const float*)d_in[3];
  float* out = (float*)d_out;
  const int B = in_sizes[1];

  int* off = (int*)d_ws;      // NMODELS+1 ints
  int* sorted = off + 160;    // B ints (aligned past off)

  prep_kernel<<<1, 256, 0, stream>>>(ids, B, off, sorted);
  linmulti_kernel<<<dim3(4, NMODELS), 256, 0, stream>>>(inp, wlut, blut, off, sorted, out);
}

// Round 4
// 107.117 us; speedup vs baseline: 1.4346x; 1.4346x over previous
//
#include <hip/hip_runtime.h>

#define NMODELS 128
#define SZ_IN 256
#define SZ_OUT 256
#define SC 16         // samples per chunk
#define NTHREADS 256  // 4 waves: 2 K-halves x 128 col-pairs
#define NWAVES (NTHREADS / 64)
#define GRIDX 4
#define MAXLIST 256

typedef __attribute__((ext_vector_type(4))) float f32x4;
typedef __attribute__((ext_vector_type(2))) float f32x2;

// One WG = (model m, chunk slice). 256 threads: col-pair = (tid&127)*2,
// K-half = tid>>7 (wave-uniform: waves 0-1 kh=0, waves 2-3 kh=1).
//
// Phase 1: DETERMINISTIC stream compaction of {b : ids[b]==m}, ordered by b,
// via ballot+popcount prefix. Every block with the same m builds the IDENTICAL
// list (R2/R3 bug: per-block atomicAdd list order diverged across blocks ->
// chunk partition by blockIdx.x missed samples -> zero rows).
//
// Phase 2 per chunk: stage A[16][256] to LDS (coalesced float4), each thread
// accumulates 16 samples x 2 cols over its 128-wide K-half (LDS broadcast
// reads, float2 coalesced weight loads), LDS-reduce the two K-halves, +bias,
// coalesced float2 store. Pure fp32.
__global__ __launch_bounds__(NTHREADS) void linmulti_v4(
    const float* __restrict__ inp, const int* __restrict__ ids,
    const float* __restrict__ wlut, const float* __restrict__ blut,
    float* __restrict__ out, int B) {
  const int m = blockIdx.y;
  const int tid = threadIdx.x;
  const int lane = tid & 63;
  const int wv = tid >> 6;

  __shared__ int list[MAXLIST];
  __shared__ int wcnt[NWAVES];
  __shared__ float As[SC * SZ_IN];  // 16 KB; reused as reduce buffer

  // ---- Phase 1: deterministic compaction (identical in every block) ----
  int base = 0;
  for (int b0 = 0; b0 < B; b0 += NTHREADS) {
    const int b = b0 + tid;
    const bool pred = (b < B) && (ids[b] == m);
    const unsigned long long mask = __ballot(pred);
    if (lane == 0) wcnt[wv] = __popcll(mask);
    __syncthreads();
    int wbase = base;
    for (int w = 0; w < wv; ++w) wbase += wcnt[w];
    if (pred) {
      const int p = wbase + __popcll(mask & ((1ULL << lane) - 1ULL));
      if (p < MAXLIST) list[p] = b;
    }
    int tot = 0;
    for (int w = 0; w < NWAVES; ++w) tot += wcnt[w];
    base += tot;
    __syncthreads();  // wcnt reused next iteration
  }
  const int cnt = (base < MAXLIST) ? base : MAXLIST;
  if (cnt == 0) return;

  // ---- Phase 2: grouped GEMV ----
  const int col2 = (tid & 127) * 2;  // this thread's 2 output cols
  const int kh = tid >> 7;           // K-half, uniform per wave
  const int ibase = kh * 128;
  const float* __restrict__ Wc =
      wlut + (size_t)m * (SZ_IN * SZ_OUT) + (size_t)ibase * SZ_OUT + col2;
  const f32x2 bias2 = *(const f32x2*)(blut + m * SZ_OUT + col2);

  const int nchunk = (cnt + SC - 1) / SC;
  for (int c = blockIdx.x; c < nchunk; c += GRIDX) {
    const int s0 = c * SC;

    __syncthreads();  // prev iteration's reduce-readers done with As
    // stage 16 rows x 256 floats = 1024 float4; 4 per thread, coalesced
#pragma unroll
    for (int v = 0; v < 4; ++v) {
      const int e4 = v * NTHREADS + tid;  // [0,1024)
      const int s = e4 >> 6;
      const int f4 = e4 & 63;
      int p = s0 + s;
      if (p > cnt - 1) p = cnt - 1;  // pad slots clamped; stores guarded
      ((f32x4*)As)[e4] = ((const f32x4*)(inp + (size_t)list[p] * SZ_IN))[f4];
    }
    __syncthreads();

    f32x2 acc[SC];
#pragma unroll
    for (int s = 0; s < SC; ++s) acc[s] = (f32x2){0.f, 0.f};

#pragma unroll 2
    for (int i0 = 0; i0 < 128; i0 += 8) {
      f32x2 w[8];
#pragma unroll
      for (int j = 0; j < 8; ++j)
        w[j] = *(const f32x2*)(Wc + (size_t)(i0 + j) * SZ_OUT);
#pragma unroll
      for (int s = 0; s < SC; ++s) {
        const float* ar = As + s * SZ_IN + ibase + i0;
        const f32x4 a0 = *(const f32x4*)ar;        // wave-uniform broadcast
        const f32x4 a1 = *(const f32x4*)(ar + 4);  // (no bank conflicts)
#pragma unroll
        for (int j = 0; j < 4; ++j) {
          acc[s][0] = fmaf(a0[j], w[j][0], acc[s][0]);
          acc[s][1] = fmaf(a0[j], w[j][1], acc[s][1]);
        }
#pragma unroll
        for (int j = 0; j < 4; ++j) {
          acc[s][0] = fmaf(a1[j], w[4 + j][0], acc[s][0]);
          acc[s][1] = fmaf(a1[j], w[4 + j][1], acc[s][1]);
        }
      }
    }

    __syncthreads();  // all compute reads of As done; reuse as reduce buf
    if (kh == 1) {
#pragma unroll
      for (int s = 0; s < SC; ++s)
        *(f32x2*)(As + s * SZ_OUT + col2) = acc[s];  // 2-way alias = free
    }
    __syncthreads();
    if (kh == 0) {
      const int rem = cnt - s0;
#pragma unroll
      for (int s = 0; s < SC; ++s) {
        if (s < rem) {
          const f32x2 oth = *(const f32x2*)(As + s * SZ_OUT + col2);
          f32x2 r;
          r[0] = acc[s][0] + oth[0] + bias2[0];
          r[1] = acc[s][1] + oth[1] + bias2[1];
          *(f32x2*)(out + (size_t)list[s0 + s] * SZ_OUT + col2) = r;
        }
      }
    }
  }
}

extern "C" void kernel_launch(void* const* d_in, const int* in_sizes, int n_in,
                              void* d_out, int out_size, void* d_ws, size_t ws_size,
                              hipStream_t stream) {
  const float* inp = (const float*)d_in[0];
  const int* ids = (const int*)d_in[1];
  const float* wlut = (const float*)d_in[2];
  const float* blut = (const float*)d_in[3];
  float* out = (float*)d_out;
  const int B = in_sizes[1];

  linmulti_v4<<<dim3(GRIDX, NMODELS), NTHREADS, 0, stream>>>(inp, ids, wlut,
                                                             blut, out, B);
}